// Round 14
// baseline (44.171 us; speedup 1.0000x reference)
//
#include <hip/hip_runtime.h>

// ---------------------------------------------------------------------------
// tNet: einsum chain is linear in x.
// k_prep (grid 512, R13-proven): blocks 0..255 build 4 rows each of W_eff
//   (bf16) entirely from LDS-staged operands; blocks 256..511 convert X->bf16.
// k_gemm (grid 16x16x4, 512 thr): LDS-FREE split-K MFMA. Wave w owns
//   16z x 32o; 8 k-steps of {1 A-frag + 2 B-frags from L2, 2 MFMA};
//   no barriers, no LDS; ~16 waves/CU TLP. Partials -> PH[kz][z][o].
//   (R10 proved LDS-free MFMA correct; R12 proved split-K grid; this is both.)
// k_out (grid 256, R13-proven): H = relu(sum_kz PH + bias1);
//   out = H @ fc2_w^T + fc2_b.
//   t5[z,d,r,t] = sum_{a,b,c,e,p,q,s} x[z,a,b,c] u1[a,d,e] b2[e,p,q]
//                                     u2[b,r,p] b1c[q,s] u3[c,t,s]
//   o = d*128+r*16+t ; i = a*128+b*16+c
// ---------------------------------------------------------------------------

using s16x8 = __attribute__((ext_vector_type(8))) short;   // 8 bf16
using f32x4 = __attribute__((ext_vector_type(4))) float;

__device__ inline short f2bf(float f) {
    unsigned u = __builtin_bit_cast(unsigned, f);
    u += 0x7fffu + ((u >> 16) & 1u);          // round-to-nearest-even
    return (short)(u >> 16);
}

// grid 512: blk<256 -> build W rows [blk*4, blk*4+4); blk>=256 -> X->bf16
__global__ __launch_bounds__(256) void k_prep(
    const float* __restrict__ x, const float* __restrict__ u1,
    const float* __restrict__ u2, const float* __restrict__ u3,
    const float* __restrict__ b2, const float* __restrict__ b1c,
    short* __restrict__ Wb, short* __restrict__ Xb) {
    const int blk = blockIdx.x;
    const int tid = threadIdx.x;

    if (blk >= 256) {                          // X f32 -> bf16
        const int base = (blk - 256) * 4096 + tid * 16;
#pragma unroll
        for (int h = 0; h < 2; ++h) {
            float4 f0 = *(const float4*)&x[base + h * 8];
            float4 f1 = *(const float4*)&x[base + h * 8 + 4];
            s16x8 v;
            v[0] = f2bf(f0.x); v[1] = f2bf(f0.y);
            v[2] = f2bf(f0.z); v[3] = f2bf(f0.w);
            v[4] = f2bf(f1.x); v[5] = f2bf(f1.y);
            v[6] = f2bf(f1.z); v[7] = f2bf(f1.w);
            *(s16x8*)&Xb[base + h * 8] = v;
        }
        return;
    }

    __shared__ float b1s[256];
    __shared__ float u1s[128];                 // u1 d-slice [a][e]
    __shared__ float u2s[64 * 17];             // [br][17] padded
    __shared__ float u3s[4096];                // full u3, linear
    __shared__ float C2t[256 * 17];            // [ep][17] padded
    __shared__ float T1s[2048];                // [a][ps]
    __shared__ float T2s[64 * 17];             // [ab][17] padded
    const int d = blk >> 5;
    const int r = (blk >> 2) & 7;
    const int t0 = (blk & 3) * 4;

    // ---- stage all small tensors (coalesced) ----
    b1s[tid] = b1c[tid];
    {
        float4* dst = (float4*)u3s;
        const float4* src = (const float4*)u3;
#pragma unroll
        for (int q = 0; q < 4; ++q) dst[tid + 256 * q] = src[tid + 256 * q];
    }
    if (tid < 64) {                            // u2 row tid -> padded
        const float4* src = (const float4*)&u2[tid * 16];
#pragma unroll
        for (int q = 0; q < 4; ++q) {
            float4 v = src[q];
            u2s[tid * 17 + q * 4 + 0] = v.x;
            u2s[tid * 17 + q * 4 + 1] = v.y;
            u2s[tid * 17 + q * 4 + 2] = v.z;
            u2s[tid * 17 + q * 4 + 3] = v.w;
        }
    }
    if (tid < 8) {                             // u1 slice: a = tid
#pragma unroll
        for (int e = 0; e < 16; ++e)
            u1s[tid * 16 + e] = u1[(tid * 8 + d) * 16 + e];
    }
    float b2r[16];                             // b2 row (e,p) = tid
    {
        const float4* src = (const float4*)&b2[tid * 16];
#pragma unroll
        for (int q = 0; q < 4; ++q) {
            float4 v = src[q];
            b2r[q * 4 + 0] = v.x; b2r[q * 4 + 1] = v.y;
            b2r[q * 4 + 2] = v.z; b2r[q * 4 + 3] = v.w;
        }
    }
    __syncthreads();

    // ---- C2: thread owns (e,p)=tid; b1s reads are wave-broadcast ----
    {
        float accs[16] = {};
#pragma unroll
        for (int q = 0; q < 16; ++q) {
            const float bq = b2r[q];
#pragma unroll
            for (int s = 0; s < 16; ++s) accs[s] += bq * b1s[q * 16 + s];
        }
#pragma unroll
        for (int s = 0; s < 16; ++s) C2t[tid * 17 + s] = accs[s];
    }
    __syncthreads();

    // ---- T1[a][ps]: thread owns ps=tid; C2t reads <=2-way ----
    {
        const int p = tid >> 4, s = tid & 15;
#pragma unroll
        for (int a = 0; a < 8; ++a) {
            float acc = 0.f;
#pragma unroll
            for (int e = 0; e < 16; ++e)
                acc += u1s[a * 16 + e] * C2t[(e * 16 + p) * 17 + s];
            T1s[a * 256 + tid] = acc;
        }
    }
    __syncthreads();

    // ---- T2[ab][s] (r fixed): T1s reads broadcast, u2s <=2-way ----
#pragma unroll
    for (int j = 0; j < 4; ++j) {
        int idx = tid + 256 * j;
        int ab = idx >> 4, s = idx & 15;
        int a = ab >> 3, b = ab & 7;
        float acc = 0.f;
#pragma unroll
        for (int p = 0; p < 16; ++p)
            acc += T1s[a * 256 + p * 16 + s] * u2s[(b * 8 + r) * 17 + p];
        T2s[ab * 17 + s] = acc;
    }
    __syncthreads();

    // ---- W rows o = blk*4 + j: u3s reads wave-broadcast, T2s 2-way ----
    {
        const int j = tid >> 6;
        const int t = t0 + j;
        const int col0 = (tid & 63) * 16;
        const int ab = col0 >> 4;
        const float* t2p = &T2s[ab * 17];
        short* wrow = &Wb[(blk * 4 + j) * 1024 + col0];
        s16x8 v0, v1;
#pragma unroll
        for (int c = 0; c < 16; ++c) {
            const float* u3p = &u3s[c * 256 + t * 16];
            float acc = 0.f;
#pragma unroll
            for (int s = 0; s < 16; ++s) acc += t2p[s] * u3p[s];
            short bf = f2bf(acc);
            if (c < 8) v0[c] = bf; else v1[c - 8] = bf;
        }
        *(s16x8*)(wrow) = v0;
        *(s16x8*)(wrow + 8) = v1;
    }
}

// ---------------------------------------------------------------------------
// LDS-free split-K MFMA GEMM. Grid (16 o, 16 z, 4 kz), 512 thr = 8 waves.
// Wave w: z-band (w>>1)*16, o-half (w&1)*32; 8 k-steps over K-slice 256;
// all operands direct from L2 (coalesced 16B/lane); ZERO barriers/LDS.
// ---------------------------------------------------------------------------
__global__ __launch_bounds__(512) void k_gemm(
    const short* __restrict__ Xb, const short* __restrict__ Wb,
    float* __restrict__ PH) {
    const int tid = threadIdx.x;
    const int lane = tid & 63;
    const int wid = tid >> 6;                  // 0..7
    const int band = wid >> 1;                 // z band (16 rows)
    const int half = wid & 1;                  // o half (32 cols)
    const int o0 = blockIdx.x * 64, z0 = blockIdx.y * 64, kz = blockIdx.z;
    const int lr = lane & 15, lk = lane >> 4;

    const short* ap  = &Xb[(z0 + band * 16 + lr) * 1024 + kz * 256 + lk * 8];
    const short* b0p = &Wb[(o0 + half * 32 + lr) * 1024 + kz * 256 + lk * 8];
    const short* b1p = b0p + 16 * 1024;

    f32x4 acc[2] = {};
#pragma unroll
    for (int k8 = 0; k8 < 8; ++k8) {
        const int off = k8 * 32;
        s16x8 av = *(const s16x8*)(ap + off);
        s16x8 b0 = *(const s16x8*)(b0p + off);
        s16x8 b1 = *(const s16x8*)(b1p + off);
        acc[0] = __builtin_amdgcn_mfma_f32_16x16x32_bf16(av, b0, acc[0], 0, 0, 0);
        acc[1] = __builtin_amdgcn_mfma_f32_16x16x32_bf16(av, b1, acc[1], 0, 0, 0);
    }

    // partial store; D layout col=lane&15, row=(lane>>4)*4+j
    float* ph = &PH[(unsigned)kz * 1048576u];
#pragma unroll
    for (int n = 0; n < 2; ++n) {
        const int col = o0 + half * 32 + n * 16 + lr;
        const int row = z0 + band * 16 + lk * 4;
#pragma unroll
        for (int j = 0; j < 4; ++j)
            ph[(row + j) * 1024 + col] = acc[n][j];
    }
}

// ---------------------------------------------------------------------------
// k_out: H = relu(sum of 4 PH slices + bias1); out = H @ fc2_w^T + fc2_b.
// 256 blocks x 256 thr; one wave per z-row (4 rows/block). No atomics.
// ---------------------------------------------------------------------------
__global__ __launch_bounds__(256) void k_out(
    const float* __restrict__ PH, const float* __restrict__ bias1,
    const float* __restrict__ W2, const float* __restrict__ fc2b,
    float* __restrict__ out) {
    __shared__ float W2s[10][1024];            // 40 KB
    const int tid = threadIdx.x;
#pragma unroll
    for (int i = 0; i < 10; ++i) {             // stage all of fc2_w
        const int idx = tid + 256 * i;         // 2560 float4
        ((float4*)W2s)[idx] = ((const float4*)W2)[idx];
    }
    __syncthreads();

    const int wid = tid >> 6, lane = tid & 63;
    const int z = blockIdx.x * 4 + wid;
    float part[10];
#pragma unroll
    for (int j = 0; j < 10; ++j) part[j] = 0.f;
#pragma unroll
    for (int i = 0; i < 16; ++i) {
        const int col = lane + 64 * i;
        float h = PH[z * 1024 + col] + PH[1048576 + z * 1024 + col]
                + PH[2097152 + z * 1024 + col] + PH[3145728 + z * 1024 + col];
        h = fmaxf(h + bias1[col], 0.f);
#pragma unroll
        for (int j = 0; j < 10; ++j) part[j] += h * W2s[j][col];
    }
#pragma unroll
    for (int j = 0; j < 10; ++j) {
#pragma unroll
        for (int off = 32; off > 0; off >>= 1) part[j] += __shfl_xor(part[j], off);
    }
    if (lane == 0) {
#pragma unroll
        for (int j = 0; j < 10; ++j) out[z * 10 + j] = part[j] + fc2b[j];
    }
}

extern "C" void kernel_launch(void* const* d_in, const int* in_sizes, int n_in,
                              void* d_out, int out_size, void* d_ws, size_t ws_size,
                              hipStream_t stream) {
    const float* x     = (const float*)d_in[0];
    const float* u1    = (const float*)d_in[1];
    const float* u2    = (const float*)d_in[2];
    const float* u3    = (const float*)d_in[3];
    const float* b2    = (const float*)d_in[4];
    const float* b1c   = (const float*)d_in[5];
    const float* bias1 = (const float*)d_in[6];
    const float* fc2w  = (const float*)d_in[7];
    const float* fc2b  = (const float*)d_in[8];
    float* out = (float*)d_out;

    short* Wb = (short*)d_ws;                                  // 2 MB bf16
    short* Xb = (short*)((char*)d_ws + 2u * 1024u * 1024u);    // 2 MB bf16
    float* PH = (float*)((char*)d_ws + 4u * 1024u * 1024u);    // 16 MB f32

    k_prep<<<512, 256, 0, stream>>>(x, u1, u2, u3, b2, b1c, Wb, Xb);
    k_gemm<<<dim3(16, 16, 4), 512, 0, stream>>>(Xb, Wb, PH);
    k_out<<<256, 256, 0, stream>>>(PH, bias1, fc2w, fc2b, out);
}

// Round 15
// 32.160 us; speedup vs baseline: 1.3735x; 1.3735x over previous
//
#include <hip/hip_runtime.h>

// ---------------------------------------------------------------------------
// tNet: einsum chain is linear in x => H = relu(X @ W_eff^T + bias1),
// out = H @ fc2_w^T + fc2_b.
//   t5[z,d,r,t] = sum_{a,b,c,e,p,q,s} x[z,a,b,c] u1[a,d,e] b2[e,p,q]
//                                     u2[b,r,p] b1c[q,s] u3[c,t,s]
//   o = d*128+r*16+t ; i = a*128+b*16+c
// k_prep (grid 256, R13-staged): builds 4 W rows/block from LDS-staged
//   operands; inits out=fc2_b. No X pass (conversion moved into k_gemm).
// k_gemm (grid 16x16, 1024 thr = 16 waves = 4 waves/SIMD): fused GEMM with
//   IN-BLOCK split-K: per iteration stage A(X f32->bf16 inline) and B 64x256
//   chunks; wave-group g (4 waves, 2x2 of 16x16x32) accumulates K-window
//   [g*64,(g+1)*64) of each chunk; 4 iterations cover K=1024. Cross-group
//   LDS reduction, then relu+bias and fused fc2 -> atomicAdd(out).
//   Rationale: R5..R14 showed cross-block split-K is a null and LDS-free is
//   -15us; the untried axis is waves/SIMD (was 1, now 4) to hide ds_read
//   latency. 67.6KB dynamic LDS.
// ---------------------------------------------------------------------------

using s16x8 = __attribute__((ext_vector_type(8))) short;   // 8 bf16
using f32x4 = __attribute__((ext_vector_type(4))) float;

__device__ inline short f2bf(float f) {
    unsigned u = __builtin_bit_cast(unsigned, f);
    u += 0x7fffu + ((u >> 16) & 1u);          // round-to-nearest-even
    return (short)(u >> 16);
}

// grid 256: build W rows [blk*4, blk*4+4) + init out = fc2_b
__global__ __launch_bounds__(256) void k_prep(
    const float* __restrict__ u1, const float* __restrict__ u2,
    const float* __restrict__ u3, const float* __restrict__ b2,
    const float* __restrict__ b1c, const float* __restrict__ fc2b,
    short* __restrict__ Wb, float* __restrict__ out) {
    const int blk = blockIdx.x;
    const int tid = threadIdx.x;

    __shared__ float b1s[256];
    __shared__ float u1s[128];                 // u1 d-slice [a][e]
    __shared__ float u2s[64 * 17];             // [br][17] padded
    __shared__ float u3s[4096];                // full u3, linear
    __shared__ float C2t[256 * 17];            // [ep][17] padded
    __shared__ float T1s[2048];                // [a][ps]
    __shared__ float T2s[64 * 17];             // [ab][17] padded
    const int d = blk >> 5;
    const int r = (blk >> 2) & 7;
    const int t0 = (blk & 3) * 4;

    if (tid < 40) {                            // out init: 256*40 = 10240
        int idx = blk * 40 + tid;
        out[idx] = fc2b[idx % 10];
    }

    // ---- stage all small tensors (coalesced) ----
    b1s[tid] = b1c[tid];
    {
        float4* dst = (float4*)u3s;
        const float4* src = (const float4*)u3;
#pragma unroll
        for (int q = 0; q < 4; ++q) dst[tid + 256 * q] = src[tid + 256 * q];
    }
    if (tid < 64) {                            // u2 row tid -> padded
        const float4* src = (const float4*)&u2[tid * 16];
#pragma unroll
        for (int q = 0; q < 4; ++q) {
            float4 v = src[q];
            u2s[tid * 17 + q * 4 + 0] = v.x;
            u2s[tid * 17 + q * 4 + 1] = v.y;
            u2s[tid * 17 + q * 4 + 2] = v.z;
            u2s[tid * 17 + q * 4 + 3] = v.w;
        }
    }
    if (tid < 8) {                             // u1 slice: a = tid
#pragma unroll
        for (int e = 0; e < 16; ++e)
            u1s[tid * 16 + e] = u1[(tid * 8 + d) * 16 + e];
    }
    float b2r[16];                             // b2 row (e,p) = tid
    {
        const float4* src = (const float4*)&b2[tid * 16];
#pragma unroll
        for (int q = 0; q < 4; ++q) {
            float4 v = src[q];
            b2r[q * 4 + 0] = v.x; b2r[q * 4 + 1] = v.y;
            b2r[q * 4 + 2] = v.z; b2r[q * 4 + 3] = v.w;
        }
    }
    __syncthreads();

    // ---- C2: thread owns (e,p)=tid ----
    {
        float accs[16] = {};
#pragma unroll
        for (int q = 0; q < 16; ++q) {
            const float bq = b2r[q];
#pragma unroll
            for (int s = 0; s < 16; ++s) accs[s] += bq * b1s[q * 16 + s];
        }
#pragma unroll
        for (int s = 0; s < 16; ++s) C2t[tid * 17 + s] = accs[s];
    }
    __syncthreads();

    // ---- T1[a][ps] ----
    {
        const int p = tid >> 4, s = tid & 15;
#pragma unroll
        for (int a = 0; a < 8; ++a) {
            float acc = 0.f;
#pragma unroll
            for (int e = 0; e < 16; ++e)
                acc += u1s[a * 16 + e] * C2t[(e * 16 + p) * 17 + s];
            T1s[a * 256 + tid] = acc;
        }
    }
    __syncthreads();

    // ---- T2[ab][s] (r fixed) ----
#pragma unroll
    for (int j = 0; j < 4; ++j) {
        int idx = tid + 256 * j;
        int ab = idx >> 4, s = idx & 15;
        int a = ab >> 3, b = ab & 7;
        float acc = 0.f;
#pragma unroll
        for (int p = 0; p < 16; ++p)
            acc += T1s[a * 256 + p * 16 + s] * u2s[(b * 8 + r) * 17 + p];
        T2s[ab * 17 + s] = acc;
    }
    __syncthreads();

    // ---- W rows o = blk*4 + j ----
    {
        const int j = tid >> 6;
        const int t = t0 + j;
        const int col0 = (tid & 63) * 16;
        const int ab = col0 >> 4;
        const float* t2p = &T2s[ab * 17];
        short* wrow = &Wb[(blk * 4 + j) * 1024 + col0];
        s16x8 v0, v1;
#pragma unroll
        for (int c = 0; c < 16; ++c) {
            const float* u3p = &u3s[c * 256 + t * 16];
            float acc = 0.f;
#pragma unroll
            for (int s = 0; s < 16; ++s) acc += t2p[s] * u3p[s];
            short bf = f2bf(acc);
            if (c < 8) v0[c] = bf; else v1[c - 8] = bf;
        }
        *(s16x8*)(wrow) = v0;
        *(s16x8*)(wrow + 8) = v1;
    }
}

// ---------------------------------------------------------------------------
// Fused GEMM, in-block split-K. Grid (16,16); 1024 thr = 16 waves (4/SIMD).
// Wave w: group g=w>>2 owns K-window [g*64,+64) of each staged 256-chunk;
// within group: (wr,wc)=((w>>1)&1, w&1) -> 32x32 via 2x2 16x16x32 frags.
// LDK=264 (2-way bank alias). Dynamic LDS 67584 B (As+Bs; reused as Hpf).
// ---------------------------------------------------------------------------
#define LDK 264

__global__ __launch_bounds__(1024) void k_gemm(
    const float* __restrict__ X, const short* __restrict__ Wb,
    const float* __restrict__ bias, const float* __restrict__ W2,
    float* __restrict__ out) {
    extern __shared__ char dsm[];
    short (*As)[LDK] = (short(*)[LDK])dsm;                 // [64][264]
    short (*Bs)[LDK] = (short(*)[LDK])(dsm + 64 * LDK * 2);// [64][264]
    float* Hpf = (float*)dsm;                              // [4][64][64] reuse
    __shared__ float W2s[10][64];

    const int tid = threadIdx.x;
    const int lane = tid & 63;
    const int w = tid >> 6;                    // 0..15
    const int g = w >> 2;                      // K-window owner
    const int wr = (w >> 1) & 1, wc = w & 1;
    const int o0 = blockIdx.x * 64, z0 = blockIdx.y * 64;
    const int lr = lane & 15, lk = lane >> 4;

    if (tid < 160) {                           // stage fc2_w tile [10][64]
        const int j = tid >> 4, c = (tid & 15) * 4;
        *(float4*)&W2s[j][c] = *(const float4*)&W2[j * 1024 + o0 + c];
    }

    const int srow = tid >> 4;                 // 0..63
    const int scol = (tid & 15) * 16;          // shorts within 256-chunk
    const float* xp = &X[(z0 + srow) * 1024 + scol];
    const short* wp = &Wb[(o0 + srow) * 1024 + scol];

    f32x4 acc[2][2] = {};

    for (int it = 0; it < 4; ++it) {
        // stage A (f32 -> bf16 inline) and B
        {
            const float* xi = xp + it * 256;
            const short* wi = wp + it * 256;
#pragma unroll
            for (int h = 0; h < 2; ++h) {
                float4 f0 = *(const float4*)(xi + h * 8);
                float4 f1 = *(const float4*)(xi + h * 8 + 4);
                s16x8 v;
                v[0] = f2bf(f0.x); v[1] = f2bf(f0.y);
                v[2] = f2bf(f0.z); v[3] = f2bf(f0.w);
                v[4] = f2bf(f1.x); v[5] = f2bf(f1.y);
                v[6] = f2bf(f1.z); v[7] = f2bf(f1.w);
                *(s16x8*)&As[srow][scol + h * 8] = v;
                *(s16x8*)&Bs[srow][scol + h * 8] = *(const s16x8*)(wi + h * 8);
            }
        }
        __syncthreads();
        // compute: group g's 64-col window, 2 ksteps
#pragma unroll
        for (int ks = 0; ks < 2; ++ks) {
            const int kb = g * 64 + ks * 32 + lk * 8;
            s16x8 a0 = *(const s16x8*)&As[wr * 32 + lr][kb];
            s16x8 a1 = *(const s16x8*)&As[wr * 32 + 16 + lr][kb];
            s16x8 b0 = *(const s16x8*)&Bs[wc * 32 + lr][kb];
            s16x8 b1 = *(const s16x8*)&Bs[wc * 32 + 16 + lr][kb];
            acc[0][0] = __builtin_amdgcn_mfma_f32_16x16x32_bf16(a0, b0, acc[0][0], 0, 0, 0);
            acc[0][1] = __builtin_amdgcn_mfma_f32_16x16x32_bf16(a0, b1, acc[0][1], 0, 0, 0);
            acc[1][0] = __builtin_amdgcn_mfma_f32_16x16x32_bf16(a1, b0, acc[1][0], 0, 0, 0);
            acc[1][1] = __builtin_amdgcn_mfma_f32_16x16x32_bf16(a1, b1, acc[1][1], 0, 0, 0);
        }
        __syncthreads();
    }

    // ---- cross-group reduction via LDS: Hpf[g][row][col] (stride 64) ----
#pragma unroll
    for (int m = 0; m < 2; ++m)
#pragma unroll
        for (int n = 0; n < 2; ++n) {
            const int row = wr * 32 + m * 16 + lk * 4;
            const int col = wc * 32 + n * 16 + lr;
#pragma unroll
            for (int j = 0; j < 4; ++j)
                Hpf[(g * 64 + row + j) * 64 + col] = acc[m][n][j];
        }
    __syncthreads();

    // ---- sum 4 groups, bias+relu, fc2 partials ----
    const int hrow = tid >> 4;                 // 0..63
    const int c4 = (tid & 15) * 4;             // 4 cols per thread
    float4 h0 = *(float4*)&Hpf[(0 * 64 + hrow) * 64 + c4];
    float4 h1 = *(float4*)&Hpf[(1 * 64 + hrow) * 64 + c4];
    float4 h2 = *(float4*)&Hpf[(2 * 64 + hrow) * 64 + c4];
    float4 h3 = *(float4*)&Hpf[(3 * 64 + hrow) * 64 + c4];
    float4 bv = *(const float4*)&bias[o0 + c4];
    float hv[4];
    hv[0] = fmaxf(h0.x + h1.x + h2.x + h3.x + bv.x, 0.f);
    hv[1] = fmaxf(h0.y + h1.y + h2.y + h3.y + bv.y, 0.f);
    hv[2] = fmaxf(h0.z + h1.z + h2.z + h3.z + bv.z, 0.f);
    hv[3] = fmaxf(h0.w + h1.w + h2.w + h3.w + bv.w, 0.f);

    float part[10];
#pragma unroll
    for (int jj = 0; jj < 10; ++jj) {
        part[jj] = hv[0] * W2s[jj][c4 + 0] + hv[1] * W2s[jj][c4 + 1]
                 + hv[2] * W2s[jj][c4 + 2] + hv[3] * W2s[jj][c4 + 3];
    }
    // reduce across the 16 threads of each row (consecutive lanes)
#pragma unroll
    for (int jj = 0; jj < 10; ++jj) {
        float p = part[jj];
        p += __shfl_xor(p, 1);
        p += __shfl_xor(p, 2);
        p += __shfl_xor(p, 4);
        p += __shfl_xor(p, 8);
        if ((lane & 15) == 0) atomicAdd(&out[(z0 + hrow) * 10 + jj], p);
    }
}

extern "C" void kernel_launch(void* const* d_in, const int* in_sizes, int n_in,
                              void* d_out, int out_size, void* d_ws, size_t ws_size,
                              hipStream_t stream) {
    const float* x     = (const float*)d_in[0];
    const float* u1    = (const float*)d_in[1];
    const float* u2    = (const float*)d_in[2];
    const float* u3    = (const float*)d_in[3];
    const float* b2    = (const float*)d_in[4];
    const float* b1c   = (const float*)d_in[5];
    const float* bias1 = (const float*)d_in[6];
    const float* fc2w  = (const float*)d_in[7];
    const float* fc2b  = (const float*)d_in[8];
    float* out = (float*)d_out;

    short* Wb = (short*)d_ws;                  // 2 MB bf16 W_eff

    k_prep<<<256, 256, 0, stream>>>(u1, u2, u3, b2, b1c, fc2b, Wb, out);
    k_gemm<<<dim3(16, 16), 1024, 64 * LDK * 2 * 2, stream>>>(x, Wb, bias1,
                                                             fc2w, out);
}

// Round 16
// 30.278 us; speedup vs baseline: 1.4588x; 1.0621x over previous
//
#include <hip/hip_runtime.h>

// ---------------------------------------------------------------------------
// tNet: einsum chain is linear in x => H = relu(X @ W_eff^T + bias1),
// out = H @ fc2_w^T + fc2_b.
//   t5[z,d,r,t] = sum_{a,b,c,e,p,q,s} x[z,a,b,c] u1[a,d,e] b2[e,p,q]
//                                     u2[b,r,p] b1c[q,s] u3[c,t,s]
//   o = d*128+r*16+t ; i = a*128+b*16+c
// k_prep (grid 512): blocks 0..255 build 4 W rows each (LDS-staged operands,
//   R13-proven) + init out=fc2_b; blocks 256..511 convert X->bf16.
//   BOTH Wb and Xb are written PRE-SWIZZLED: within each 16-chunk (128-col)
//   group, chunk c of row r is stored at position c^(r&15). This makes the
//   gemm's linear global_load_lds staging land a layout whose ds_read
//   (position (chunk)^(row&15)) is ~2-way-bank-conflict-free (m173 pattern).
// k_gemm (grid 16x16, 256 thr): 64x64 tile, BK=128, DOUBLE-BUFFERED LDS with
//   __builtin_amdgcn_global_load_lds width=16 staging, counted
//   s_waitcnt vmcnt(8) + raw s_barrier (loads stay in flight across
//   barriers - guide T3/T4 minimum 2-phase). Fused fc2 epilogue -> atomicAdd.
// ---------------------------------------------------------------------------

using s16x8 = __attribute__((ext_vector_type(8))) short;   // 8 bf16
using f32x4 = __attribute__((ext_vector_type(4))) float;

__device__ inline short f2bf(float f) {
    unsigned u = __builtin_bit_cast(unsigned, f);
    u += 0x7fffu + ((u >> 16) & 1u);          // round-to-nearest-even
    return (short)(u >> 16);
}

__device__ inline void gload16(const short* g, short* l) {
    __builtin_amdgcn_global_load_lds(
        (__attribute__((address_space(1))) void*)g,
        (__attribute__((address_space(3))) void*)l, 16, 0, 0);
}

// grid 512: blk<256 -> build W rows [blk*4,+4) + init out; blk>=256 -> X->bf16
__global__ __launch_bounds__(256) void k_prep(
    const float* __restrict__ x, const float* __restrict__ u1,
    const float* __restrict__ u2, const float* __restrict__ u3,
    const float* __restrict__ b2, const float* __restrict__ b1c,
    const float* __restrict__ fc2b, short* __restrict__ Wb,
    short* __restrict__ Xb, float* __restrict__ out) {
    const int blk = blockIdx.x;
    const int tid = threadIdx.x;

    if (blk >= 256) {                          // X f32 -> bf16, swizzled
        const int base = (blk - 256) * 4096 + tid * 16;
        const int z = base >> 10;
        const int col = base & 1023;
        const int c = col >> 3, g = c >> 4, c4 = c & 15, mz = z & 15;
        short* xbase = &Xb[z * 1024 + g * 128];
#pragma unroll
        for (int h = 0; h < 2; ++h) {
            float4 f0 = *(const float4*)&x[base + h * 8];
            float4 f1 = *(const float4*)&x[base + h * 8 + 4];
            s16x8 v;
            v[0] = f2bf(f0.x); v[1] = f2bf(f0.y);
            v[2] = f2bf(f0.z); v[3] = f2bf(f0.w);
            v[4] = f2bf(f1.x); v[5] = f2bf(f1.y);
            v[6] = f2bf(f1.z); v[7] = f2bf(f1.w);
            *(s16x8*)(xbase + ((c4 + h) ^ mz) * 8) = v;
        }
        return;
    }

    __shared__ float b1s[256];
    __shared__ float u1s[128];                 // u1 d-slice [a][e]
    __shared__ float u2s[64 * 17];             // [br][17] padded
    __shared__ float u3s[4096];                // full u3, linear
    __shared__ float C2t[256 * 17];            // [ep][17] padded
    __shared__ float T1s[2048];                // [a][ps]
    __shared__ float T2s[64 * 17];             // [ab][17] padded
    const int d = blk >> 5;
    const int r = (blk >> 2) & 7;
    const int t0 = (blk & 3) * 4;

    if (tid < 40) {                            // out init: 256*40 = 10240
        int idx = blk * 40 + tid;
        out[idx] = fc2b[idx % 10];
    }

    // ---- stage all small tensors (coalesced) ----
    b1s[tid] = b1c[tid];
    {
        float4* dst = (float4*)u3s;
        const float4* src = (const float4*)u3;
#pragma unroll
        for (int q = 0; q < 4; ++q) dst[tid + 256 * q] = src[tid + 256 * q];
    }
    if (tid < 64) {                            // u2 row tid -> padded
        const float4* src = (const float4*)&u2[tid * 16];
#pragma unroll
        for (int q = 0; q < 4; ++q) {
            float4 v = src[q];
            u2s[tid * 17 + q * 4 + 0] = v.x;
            u2s[tid * 17 + q * 4 + 1] = v.y;
            u2s[tid * 17 + q * 4 + 2] = v.z;
            u2s[tid * 17 + q * 4 + 3] = v.w;
        }
    }
    if (tid < 8) {                             // u1 slice: a = tid
#pragma unroll
        for (int e = 0; e < 16; ++e)
            u1s[tid * 16 + e] = u1[(tid * 8 + d) * 16 + e];
    }
    float b2r[16];                             // b2 row (e,p) = tid
    {
        const float4* src = (const float4*)&b2[tid * 16];
#pragma unroll
        for (int q = 0; q < 4; ++q) {
            float4 v = src[q];
            b2r[q * 4 + 0] = v.x; b2r[q * 4 + 1] = v.y;
            b2r[q * 4 + 2] = v.z; b2r[q * 4 + 3] = v.w;
        }
    }
    __syncthreads();

    // ---- C2: thread owns (e,p)=tid ----
    {
        float accs[16] = {};
#pragma unroll
        for (int q = 0; q < 16; ++q) {
            const float bq = b2r[q];
#pragma unroll
            for (int s = 0; s < 16; ++s) accs[s] += bq * b1s[q * 16 + s];
        }
#pragma unroll
        for (int s = 0; s < 16; ++s) C2t[tid * 17 + s] = accs[s];
    }
    __syncthreads();

    // ---- T1[a][ps] ----
    {
        const int p = tid >> 4, s = tid & 15;
#pragma unroll
        for (int a = 0; a < 8; ++a) {
            float acc = 0.f;
#pragma unroll
            for (int e = 0; e < 16; ++e)
                acc += u1s[a * 16 + e] * C2t[(e * 16 + p) * 17 + s];
            T1s[a * 256 + tid] = acc;
        }
    }
    __syncthreads();

    // ---- T2[ab][s] (r fixed) ----
#pragma unroll
    for (int j = 0; j < 4; ++j) {
        int idx = tid + 256 * j;
        int ab = idx >> 4, s = idx & 15;
        int a = ab >> 3, b = ab & 7;
        float acc = 0.f;
#pragma unroll
        for (int p = 0; p < 16; ++p)
            acc += T1s[a * 256 + p * 16 + s] * u2s[(b * 8 + r) * 17 + p];
        T2s[ab * 17 + s] = acc;
    }
    __syncthreads();

    // ---- W rows o = blk*4 + j, swizzled store ----
    {
        const int j = tid >> 6;
        const int o = blk * 4 + j;
        const int t = t0 + j;
        const int col0 = (tid & 63) * 16;
        const int ab = col0 >> 4;
        const float* t2p = &T2s[ab * 17];
        s16x8 v0, v1;
#pragma unroll
        for (int c = 0; c < 16; ++c) {
            const float* u3p = &u3s[c * 256 + t * 16];
            float acc = 0.f;
#pragma unroll
            for (int s = 0; s < 16; ++s) acc += t2p[s] * u3p[s];
            short bf = f2bf(acc);
            if (c < 8) v0[c] = bf; else v1[c - 8] = bf;
        }
        const int cc = col0 >> 3;              // even chunk index
        const int g = cc >> 4, c4 = cc & 15, mo = o & 15;
        short* wbase = &Wb[o * 1024 + g * 128];
        *(s16x8*)(wbase + ((c4    ) ^ mo) * 8) = v0;
        *(s16x8*)(wbase + ((c4 + 1) ^ mo) * 8) = v1;
    }
}

// ---------------------------------------------------------------------------
// Double-buffered gload_lds MFMA GEMM + fused fc2. Grid (16,16), 256 thr =
// 4 waves (2x2); 64x64 tile; BK=128; 8 iters; 64KB LDS -> 2 blocks/CU.
// Counted vmcnt(8) keeps next tile's 8 loads in flight across barriers.
// ---------------------------------------------------------------------------
__global__ __launch_bounds__(256) void k_gemm(
    const short* __restrict__ Xb, const short* __restrict__ Wb,
    const float* __restrict__ bias, const float* __restrict__ W2,
    float* __restrict__ out) {
    __shared__ short AB[2][2][64][128];        // [buf][A/B][row][col] 64KB
    __shared__ float W2s[10][64];
    const int tid = threadIdx.x;
    const int ln = tid & 63;
    const int wv = tid >> 6, wr = wv >> 1, wc = wv & 1;
    const int o0 = blockIdx.x * 64, z0 = blockIdx.y * 64;
    const int lr = ln & 15, lk = ln >> 4;

    if (tid < 160) {                           // stage fc2_w tile [10][64]
        const int j = tid >> 4, c = (tid & 15) * 4;
        *(float4*)&W2s[j][c] = *(const float4*)&W2[j * 1024 + o0 + c];
    }

    // STAGE(buf,k0): 4 waves x 4 issues x 64 lanes x 16B = 32KB (A+B tiles).
    // Issue q of wave wv covers rows (wv*4+q)*4 + lk, position lr (source is
    // pre-swizzled in global, so linear copy = swizzled LDS layout).
#define STAGE(buf, k0)                                                        \
    do {                                                                      \
        _Pragma("unroll")                                                     \
        for (int q = 0; q < 4; ++q) {                                         \
            const int rr = (wv * 4 + q) * 4 + lk;                             \
            gload16(&Xb[(z0 + rr) * 1024 + (k0) + lr * 8],                    \
                    &AB[buf][0][(wv * 4 + q) * 4][0]);                        \
            gload16(&Wb[(o0 + rr) * 1024 + (k0) + lr * 8],                    \
                    &AB[buf][1][(wv * 4 + q) * 4][0]);                        \
        }                                                                     \
    } while (0)

    f32x4 acc[2][2] = {};
    STAGE(0, 0);                               // prologue: 8 loads in flight

    for (int t = 0; t < 8; ++t) {
        const int cur = t & 1;
        if (t < 7) {
            STAGE(cur ^ 1, (t + 1) * 128);     // issue next tile (+8)
            asm volatile("s_waitcnt vmcnt(8)" ::: "memory");  // cur's 8 done
        } else {
            asm volatile("s_waitcnt vmcnt(0)" ::: "memory");
        }
        __builtin_amdgcn_s_barrier();          // all waves' cur staged
#pragma unroll
        for (int ks = 0; ks < 4; ++ks) {
            const int pa = (((ks * 4) + lk) ^ lr) * 8;   // swizzled position
            s16x8 a0 = *(const s16x8*)&AB[cur][0][wr * 32 + lr][pa];
            s16x8 a1 = *(const s16x8*)&AB[cur][0][wr * 32 + 16 + lr][pa];
            s16x8 b0 = *(const s16x8*)&AB[cur][1][wc * 32 + lr][pa];
            s16x8 b1 = *(const s16x8*)&AB[cur][1][wc * 32 + 16 + lr][pa];
            acc[0][0] = __builtin_amdgcn_mfma_f32_16x16x32_bf16(a0, b0, acc[0][0], 0, 0, 0);
            acc[0][1] = __builtin_amdgcn_mfma_f32_16x16x32_bf16(a0, b1, acc[0][1], 0, 0, 0);
            acc[1][0] = __builtin_amdgcn_mfma_f32_16x16x32_bf16(a1, b0, acc[1][0], 0, 0, 0);
            acc[1][1] = __builtin_amdgcn_mfma_f32_16x16x32_bf16(a1, b1, acc[1][1], 0, 0, 0);
        }
        __builtin_amdgcn_s_barrier();          // cur consumed; safe to restage
        __builtin_amdgcn_sched_barrier(0);     // pin next STAGE after barrier
    }
#undef STAGE

    // ---- epilogue: relu H-tile into LDS (alias AB: [64][68] f32) ----
    float* Ht = (float*)AB;
#pragma unroll
    for (int m = 0; m < 2; ++m)
#pragma unroll
        for (int n = 0; n < 2; ++n) {
            const int row = wr * 32 + m * 16 + lk * 4;
            const int col = wc * 32 + n * 16 + lr;
            const float bv = bias[o0 + col];
#pragma unroll
            for (int j = 0; j < 4; ++j)
                Ht[(row + j) * 68 + col] = fmaxf(acc[m][n][j] + bv, 0.f);
        }
    __syncthreads();

    // ---- fused fc2: 4 threads per z-row over 64 cols -> atomicAdd(out) ----
    const int zr = tid >> 2, q = tid & 3;
    float part[10];
#pragma unroll
    for (int jj = 0; jj < 10; ++jj) part[jj] = 0.f;
#pragma unroll
    for (int cc = 0; cc < 16; ++cc) {
        const int cl = q + 4 * cc;
        const float hv = Ht[zr * 68 + cl];
#pragma unroll
        for (int jj = 0; jj < 10; ++jj) part[jj] += hv * W2s[jj][cl];
    }
#pragma unroll
    for (int jj = 0; jj < 10; ++jj) {
        float p = part[jj];
        p += __shfl_xor(p, 1);
        p += __shfl_xor(p, 2);
        if (q == 0) atomicAdd(&out[(z0 + zr) * 10 + jj], p);
    }
}

extern "C" void kernel_launch(void* const* d_in, const int* in_sizes, int n_in,
                              void* d_out, int out_size, void* d_ws, size_t ws_size,
                              hipStream_t stream) {
    const float* x     = (const float*)d_in[0];
    const float* u1    = (const float*)d_in[1];
    const float* u2    = (const float*)d_in[2];
    const float* u3    = (const float*)d_in[3];
    const float* b2    = (const float*)d_in[4];
    const float* b1c   = (const float*)d_in[5];
    const float* bias1 = (const float*)d_in[6];
    const float* fc2w  = (const float*)d_in[7];
    const float* fc2b  = (const float*)d_in[8];
    float* out = (float*)d_out;

    short* Wb = (short*)d_ws;                                  // 2 MB bf16
    short* Xb = (short*)((char*)d_ws + 2u * 1024u * 1024u);    // 2 MB bf16

    k_prep<<<512, 256, 0, stream>>>(x, u1, u2, u3, b2, b1c, fc2b, Wb, Xb, out);
    k_gemm<<<dim3(16, 16), 256, 0, stream>>>(Xb, Wb, bias1, fc2w, out);
}